// Round 14
// baseline (44.559 us; speedup 1.0000x reference)
//
#include <hip/hip_runtime.h>

// Problem constants (B=1)
#define H 8
#define S 4096
#define D 64          // D1 == D2 == 64
#define C 64          // chunk length
#define NC (S / C)    // 64 chunks per head
#define DD (D * D)
#define PITCH 72      // bf16 LDS row pitch (144B, 16B-aligned)
#define NBLK (NC * H) // 512 blocks

typedef short bf16x8 __attribute__((ext_vector_type(8)));
typedef float f32x4 __attribute__((ext_vector_type(4)));
typedef unsigned uint4v __attribute__((ext_vector_type(4)));

struct alignas(16) F4 { float v[4]; };
struct alignas(16) U16 { unsigned long long a, b; };

__device__ inline unsigned short rne_bf16(float x) {
  unsigned u = __builtin_bit_cast(unsigned, x);
  unsigned r = u + 0x7fffu + ((u >> 16) & 1u);
  return (unsigned short)(r >> 16);
}

// All cross-block data moves through the LLC via relaxed AGENT-scope atomics
// (sc1 write-through stores, sc1 bypass loads). No line is ever cached on
// either side -> no buffer_inv / wbl2 fences needed anywhere.
__device__ inline unsigned long long ld64_llc(const void* p) {
  return __hip_atomic_load((const unsigned long long*)p,
                           __ATOMIC_RELAXED, __HIP_MEMORY_SCOPE_AGENT);
}
__device__ inline void st32_llc(unsigned* p, unsigned v) {
  __hip_atomic_store(p, v, __ATOMIC_RELAXED, __HIP_MEMORY_SCOPE_AGENT);
}
__device__ inline void stf_llc(float* p, float v) {
  __hip_atomic_store(p, v, __ATOMIC_RELAXED, __HIP_MEMORY_SCOPE_AGENT);
}

// Flush-free grid barrier (R8-proven): relaxed add + relaxed spin polls.
// __syncthreads before the arrive drains the block's vmcnt (sc1 stores are
// LLC-visible on retirement); no cache maintenance on any path.
__device__ inline void grid_barrier(unsigned* cnt) {
  __syncthreads();
  if (threadIdx.x == 0) {
    __hip_atomic_fetch_add(cnt, 1u, __ATOMIC_RELAXED, __HIP_MEMORY_SCOPE_AGENT);
    while (__hip_atomic_load(cnt, __ATOMIC_RELAXED, __HIP_MEMORY_SCOPE_AGENT) <
           (unsigned)NBLK) {
      __builtin_amdgcn_s_sleep(2);
    }
  }
  __syncthreads();
}

// ---------------------------------------------------------------------------
// Fused kernel (R8 structure, zero fences). Block b -> (ch = b&63, h = b>>6).
// Phase 1: stage q_bar/k_bar/k_barT/vT, chunk-state MFMA -> wsF (f32, sc1),
//   A = tril(q_bar k_bar^T), partial O = A*V kept in registers.
// barrier -> Phase 2: per-head exclusive scan (blocks 0..255, wave 0),
//   sc1 loads of wsF, packed-bf16 sc1 stores to ws2.
// barrier -> Phase 3: O += q_bar*S0 (sc1 b64 loads), rmsnorm, store.
// ---------------------------------------------------------------------------
__global__ __launch_bounds__(256, 2) void k_fused(
    const float* __restrict__ q, const float* __restrict__ k,
    const float* __restrict__ v,
    const float* __restrict__ coef_q, const float* __restrict__ coef_k,
    const float* __restrict__ mask_normer,
    float* __restrict__ wsF, unsigned* __restrict__ ws2,
    unsigned* __restrict__ bar, float* __restrict__ out) {
  const int b = blockIdx.x;
  const int ch = b & 63, h = b >> 6;
  const int t = threadIdx.x;

  __shared__ alignas(16) short qb[C * PITCH];    // q_bar  [i][a]
  __shared__ alignas(16) short kbf[C * PITCH];   // k_bar  [j][a]
  __shared__ alignas(16) short vT[C * PITCH];    // v^T    [c][i]
  __shared__ alignas(16) short kT[C * PITCH];    // k_bar^T[a][i]
  __shared__ alignas(16) short Ab[C * PITCH];    // A      [i][j]

  const size_t base = (size_t)(h * S + ch * C) * D;
  const float* qp = q + base;
  const float* kp = k + base;
  const float* vp = v + base;
  const float* cqp = coef_q + h * S + ch * C;
  const float* ckp = coef_k + h * S + ch * C;
  const float* mnp = mask_normer + h * S + ch * C;

  // ---- Phase 1 staging: rows (q_bar, k_bar) ----
  {
    const int i = t >> 2, c0 = (t & 3) * 16;
    const float sq = cqp[i] / mnp[i];
    const float sk = ckp[i];
#pragma unroll
    for (int g = 0; g < 2; ++g) {
      bf16x8 wq, wk;
#pragma unroll
      for (int u0 = 0; u0 < 8; u0 += 4) {
        F4 qv = *reinterpret_cast<const F4*>(qp + i * D + c0 + 8 * g + u0);
        F4 kv = *reinterpret_cast<const F4*>(kp + i * D + c0 + 8 * g + u0);
#pragma unroll
        for (int u = 0; u < 4; ++u) {
          wq[u0 + u] = (short)rne_bf16(qv.v[u] * sq);
          wk[u0 + u] = (short)rne_bf16(kv.v[u] * sk);
        }
      }
      *reinterpret_cast<bf16x8*>(&qb[i * PITCH + c0 + 8 * g]) = wq;
      *reinterpret_cast<bf16x8*>(&kbf[i * PITCH + c0 + 8 * g]) = wk;
    }
  }
  // ---- Phase 1 staging: columns (k_bar^T, v^T), coalesced row reads ----
  {
    const int col = t & 63, i0 = 16 * (t >> 6);
    unsigned prk[8], prv[8];
#pragma unroll
    for (int u2 = 0; u2 < 8; ++u2) {
      const int ia = i0 + 2 * u2, ib = ia + 1;
      float k0 = kp[ia * D + col] * ckp[ia];
      float k1 = kp[ib * D + col] * ckp[ib];
      float v0 = vp[ia * D + col];
      float v1 = vp[ib * D + col];
      prk[u2] = (unsigned)rne_bf16(k0) | ((unsigned)rne_bf16(k1) << 16);
      prv[u2] = (unsigned)rne_bf16(v0) | ((unsigned)rne_bf16(v1) << 16);
    }
#pragma unroll
    for (int g = 0; g < 2; ++g) {
      uint4v wk = {prk[4 * g], prk[4 * g + 1], prk[4 * g + 2], prk[4 * g + 3]};
      uint4v wv = {prv[4 * g], prv[4 * g + 1], prv[4 * g + 2], prv[4 * g + 3]};
      *reinterpret_cast<uint4v*>(&kT[col * PITCH + i0 + 8 * g]) = wk;
      *reinterpret_cast<uint4v*>(&vT[col * PITCH + i0 + 8 * g]) = wv;
    }
  }
  __syncthreads();

  const int lane = t & 63, w = t >> 6;
  const int arow = lane & 15, kg = lane >> 4;
  const int rbase = (16 * w + arow) * PITCH + 8 * kg;

  // ---- chunk-state MFMA: state[c][a] = sum_i v[i][c] k_bar[i][a] -> LLC ----
  {
    bf16x8 a0 = *reinterpret_cast<const bf16x8*>(&vT[rbase]);
    bf16x8 a1 = *reinterpret_cast<const bf16x8*>(&vT[rbase + 32]);
    float* dst = wsF + (size_t)(h * NC + ch) * DD;
#pragma unroll
    for (int n = 0; n < 4; ++n) {
      const int bb = (16 * n + arow) * PITCH + 8 * kg;
      bf16x8 b0 = *reinterpret_cast<const bf16x8*>(&kT[bb]);
      bf16x8 b1 = *reinterpret_cast<const bf16x8*>(&kT[bb + 32]);
      f32x4 z = {0.f, 0.f, 0.f, 0.f};
      z = __builtin_amdgcn_mfma_f32_16x16x32_bf16(a0, b0, z, 0, 0, 0);
      z = __builtin_amdgcn_mfma_f32_16x16x32_bf16(a1, b1, z, 0, 0, 0);
#pragma unroll
      for (int r = 0; r < 4; ++r)
        stf_llc(&dst[(16 * w + 4 * kg + r) * D + 16 * n + arow], z[r]);
    }
  }

  // ---- A-stage (scan-independent): A = tril(q_bar k_bar^T) ----
  bf16x8 qa0 = *reinterpret_cast<const bf16x8*>(&qb[rbase]);
  bf16x8 qa1 = *reinterpret_cast<const bf16x8*>(&qb[rbase + 32]);
  {
    f32x4 accA[4];
#pragma unroll
    for (int n = 0; n < 4; ++n) {
      const int bb = (16 * n + arow) * PITCH + 8 * kg;
      bf16x8 b0 = *reinterpret_cast<const bf16x8*>(&kbf[bb]);
      bf16x8 b1 = *reinterpret_cast<const bf16x8*>(&kbf[bb + 32]);
      f32x4 z = {0.f, 0.f, 0.f, 0.f};
      z = __builtin_amdgcn_mfma_f32_16x16x32_bf16(qa0, b0, z, 0, 0, 0);
      z = __builtin_amdgcn_mfma_f32_16x16x32_bf16(qa1, b1, z, 0, 0, 0);
      accA[n] = z;
    }
#pragma unroll
    for (int n = 0; n < 4; ++n)
#pragma unroll
      for (int r = 0; r < 4; ++r) {
        int i = 4 * kg + r;
        int j = 16 * n + arow;
        float x = (j <= 16 * w + i) ? accA[n][r] : 0.f;
        Ab[(16 * w + i) * PITCH + j] = (short)rne_bf16(x);
      }
  }
  // same-wave read-after-write on Ab rows 16w.. (no barrier needed)
  bf16x8 aa0 = *reinterpret_cast<const bf16x8*>(&Ab[rbase]);
  bf16x8 aa1 = *reinterpret_cast<const bf16x8*>(&Ab[rbase + 32]);

  // ---- partial O = A*V (scan-independent), kept in registers ----
  f32x4 accO[4];
#pragma unroll
  for (int n = 0; n < 4; ++n) {
    const int bb = (16 * n + arow) * PITCH + 8 * kg;
    bf16x8 v0 = *reinterpret_cast<const bf16x8*>(&vT[bb]);
    bf16x8 v1 = *reinterpret_cast<const bf16x8*>(&vT[bb + 32]);
    f32x4 z = {0.f, 0.f, 0.f, 0.f};
    z = __builtin_amdgcn_mfma_f32_16x16x32_bf16(aa0, v0, z, 0, 0, 0);
    z = __builtin_amdgcn_mfma_f32_16x16x32_bf16(aa1, v1, z, 0, 0, 0);
    accO[n] = z;
  }

  grid_barrier(&bar[0]);

  // ---- Phase 2: per-head exclusive scan (blocks 0..255, wave 0) ----
  if (b < 256 && t < 64) {
    const int sh = b >> 5, seg = b & 31;
    const int e0 = seg * 64 + t;   // output dword index 0..2047 (2 elems)
    const float* src = wsF + (size_t)sh * NC * DD + 2 * e0;
    unsigned* dst = ws2 + (size_t)sh * NC * (DD / 2) + e0;
    float run0 = 0.f, run1 = 0.f;
    for (int b2 = 0; b2 < NC; b2 += 32) {
      unsigned long long x[32];
#pragma unroll
      for (int u = 0; u < 32; ++u)
        x[u] = ld64_llc(src + (size_t)(b2 + u) * DD);
#pragma unroll
      for (int u = 0; u < 32; ++u) {
        unsigned pk = (unsigned)rne_bf16(run0) | ((unsigned)rne_bf16(run1) << 16);
        st32_llc(&dst[(size_t)(b2 + u) * (DD / 2)], pk);
        run0 += __builtin_bit_cast(float, (unsigned)(x[u] & 0xffffffffu));
        run1 += __builtin_bit_cast(float, (unsigned)(x[u] >> 32));
      }
    }
  }

  grid_barrier(&bar[1]);

  // ---- Phase 3: O += q_bar * S0 (sc1 b64 loads of packed bf16) ----
  {
    const unsigned long long* s0q =
        reinterpret_cast<const unsigned long long*>(ws2) +
        (size_t)(h * NC + ch) * (DD / 4);
#pragma unroll
    for (int n = 0; n < 4; ++n) {
      const int qi = (16 * n + arow) * 16 + 2 * kg;
      U16 u0 = {ld64_llc(&s0q[qi]), ld64_llc(&s0q[qi + 1])};
      U16 u1 = {ld64_llc(&s0q[qi + 8]), ld64_llc(&s0q[qi + 9])};
      bf16x8 h0 = __builtin_bit_cast(bf16x8, u0);
      bf16x8 h1 = __builtin_bit_cast(bf16x8, u1);
      accO[n] = __builtin_amdgcn_mfma_f32_16x16x32_bf16(qa0, h0, accO[n], 0, 0, 0);
      accO[n] = __builtin_amdgcn_mfma_f32_16x16x32_bf16(qa1, h1, accO[n], 0, 0, 0);
    }
  }

  // ---- epilogue: rmsnorm per row (row lives in one quarter-wave) ----
  float* op = out + base;
#pragma unroll
  for (int r = 0; r < 4; ++r) {
    const int i = 16 * w + 4 * kg + r;
    float ss = 0.f;
#pragma unroll
    for (int n = 0; n < 4; ++n) ss += accO[n][r] * accO[n][r];
#pragma unroll
    for (int off = 1; off < 16; off <<= 1) ss += __shfl_xor(ss, off);
    const float sc = rsqrtf(ss * (1.0f / D) + 1e-6f);
#pragma unroll
    for (int n = 0; n < 4; ++n)
      op[(size_t)i * D + 16 * n + arow] = accO[n][r] * sc;
  }
}

// ---------------------------------------------------------------------------
extern "C" void kernel_launch(void* const* d_in, const int* in_sizes, int n_in,
                              void* d_out, int out_size, void* d_ws, size_t ws_size,
                              hipStream_t stream) {
  (void)in_sizes; (void)n_in; (void)out_size; (void)ws_size;
  const float* q  = (const float*)d_in[0];
  const float* k  = (const float*)d_in[1];
  const float* v  = (const float*)d_in[2];
  const float* cq = (const float*)d_in[3];
  const float* ck = (const float*)d_in[4];
  const float* mn = (const float*)d_in[5];
  float* out = (float*)d_out;

  float* wsF    = (float*)d_ws;                                   // 8 MiB f32 states
  unsigned* ws2 = (unsigned*)((char*)d_ws + 8u * 1024u * 1024u);  // 4 MiB packed bf16
  unsigned* bar = (unsigned*)((char*)d_ws + 16u * 1024u * 1024u); // 2 counters

  hipMemsetAsync(bar, 0, 2 * sizeof(unsigned), stream);
  k_fused<<<dim3(NBLK), dim3(256), 0, stream>>>(q, k, v, cq, ck, mn, wsF, ws2, bar, out);
}

// Round 15
// 24.128 us; speedup vs baseline: 1.8468x; 1.8468x over previous
//
#include <hip/hip_runtime.h>

// Problem constants (B=1)
#define H 8
#define S 4096
#define D 64          // D1 == D2 == 64
#define C 64          // chunk length
#define NC (S / C)    // 64 chunks per head
#define DD (D * D)
#define PITCH 72      // bf16 LDS row pitch (144B, 16B-aligned, 4-bank rotation)

typedef short bf16x8 __attribute__((ext_vector_type(8)));
typedef float f32x4 __attribute__((ext_vector_type(4)));
typedef unsigned uint4v __attribute__((ext_vector_type(4)));

struct alignas(16) F4 { float v[4]; };

__device__ inline unsigned short rne_bf16(float x) {
  unsigned u = __builtin_bit_cast(unsigned, x);
  unsigned r = u + 0x7fffu + ((u >> 16) & 1u);
  return (unsigned short)(r >> 16);
}
__device__ inline float bf16_to_f(unsigned hw) {
  return __builtin_bit_cast(float, hw << 16);
}

// ---------------------------------------------------------------------------
// Kernel 1 (512 thr, 8 waves): per-chunk state via MFMA, bf16 out:
//   wsKV[h][ch][c][a] = bf16( sum_i v[i][c] * k_bar[i][a] )
// ---------------------------------------------------------------------------
__global__ __launch_bounds__(512, 2) void k_chunk_sums(
    const float* __restrict__ k, const float* __restrict__ v,
    const float* __restrict__ coef_k, unsigned short* __restrict__ wsKV) {
  const int ch = blockIdx.x, h = blockIdx.y, t = threadIdx.x;
  __shared__ alignas(16) short kT[C * PITCH];   // k_bar^T [a][i]
  __shared__ alignas(16) short vT[C * PITCH];   // v^T     [c][i]

  const float* kp = k + (size_t)(h * S + ch * C) * D;
  const float* vp = v + (size_t)(h * S + ch * C) * D;
  const float* ck = coef_k + h * S + ch * C;

  // staging: col = t&63; grp = t>>6: grp<4 -> kT (i0=16*grp), else vT
  {
    const int col = t & 63, grp = t >> 6;
    const bool isK = grp < 4;
    const int i0 = (grp & 3) * 16;
    const float* src = isK ? kp : vp;
    short* dstT = isK ? kT : vT;
    unsigned pr[8];
#pragma unroll
    for (int u2 = 0; u2 < 8; ++u2) {
      const int ia = i0 + 2 * u2, ib = ia + 1;
      float x0 = src[ia * D + col];
      float x1 = src[ib * D + col];
      if (isK) { x0 *= ck[ia]; x1 *= ck[ib]; }
      pr[u2] = (unsigned)rne_bf16(x0) | ((unsigned)rne_bf16(x1) << 16);
    }
#pragma unroll
    for (int g = 0; g < 2; ++g) {
      uint4v wv = {pr[4 * g], pr[4 * g + 1], pr[4 * g + 2], pr[4 * g + 3]};
      *reinterpret_cast<uint4v*>(&dstT[col * PITCH + i0 + 8 * g]) = wv;
    }
  }
  __syncthreads();

  // MFMA: wave w -> row-tile m = w>>1 (c), col-tiles n0..n0+1 (a)
  const int lane = t & 63, w = t >> 6;
  const int arow = lane & 15, kg = lane >> 4;
  const int m = w >> 1, n0 = 2 * (w & 1);
  const int abase = (16 * m + arow) * PITCH + 8 * kg;
  bf16x8 a0 = *reinterpret_cast<const bf16x8*>(&vT[abase]);
  bf16x8 a1 = *reinterpret_cast<const bf16x8*>(&vT[abase + 32]);
  unsigned short* dst = wsKV + (size_t)(h * NC + ch) * DD;
#pragma unroll
  for (int nn = 0; nn < 2; ++nn) {
    const int n = n0 + nn;
    const int bb = (16 * n + arow) * PITCH + 8 * kg;
    bf16x8 b0 = *reinterpret_cast<const bf16x8*>(&kT[bb]);
    bf16x8 b1 = *reinterpret_cast<const bf16x8*>(&kT[bb + 32]);
    f32x4 z = {0.f, 0.f, 0.f, 0.f};
    z = __builtin_amdgcn_mfma_f32_16x16x32_bf16(a0, b0, z, 0, 0, 0);
    z = __builtin_amdgcn_mfma_f32_16x16x32_bf16(a1, b1, z, 0, 0, 0);
#pragma unroll
    for (int r = 0; r < 4; ++r)
      dst[(16 * m + 4 * kg + r) * D + 16 * n + arow] = rne_bf16(z[r]);
  }
}

// ---------------------------------------------------------------------------
// Kernel 2: exclusive prefix scan across chunks (per head), bf16 in/out,
// f32 running sum, 32-deep load batching.
// ---------------------------------------------------------------------------
__global__ __launch_bounds__(64) void k_scan(unsigned* __restrict__ wsKV) {
  const int seg = blockIdx.x, h = blockIdx.y, t = threadIdx.x;
  const int e0 = seg * 64 + t;               // dword index within 2048-dword matrix
  float run0 = 0.f, run1 = 0.f;
  for (int base = 0; base < NC; base += 32) {
    unsigned x[32];
#pragma unroll
    for (int u = 0; u < 32; ++u)
      x[u] = wsKV[(size_t)(h * NC + base + u) * 2048 + e0];
#pragma unroll
    for (int u = 0; u < 32; ++u) {
      wsKV[(size_t)(h * NC + base + u) * 2048 + e0] =
          (unsigned)rne_bf16(run0) | ((unsigned)rne_bf16(run1) << 16);
      run0 += bf16_to_f(x[u] & 0xffffu);
      run1 += bf16_to_f(x[u] >> 16);
    }
  }
}

// ---------------------------------------------------------------------------
// Kernel 3 (512 thr, 8 waves): per-chunk output via MFMA.
//   A = tril(q_bar K_bar^T);  O = q_bar*S0 + A*V;  rmsnorm(O).
// Wave w: row-tile m = w>>1, col-pair n0 = 2*(w&1) (A-stage cols / O cols).
// S0 fragments loaded straight from global (no LDS staging).
// ---------------------------------------------------------------------------
__global__ __launch_bounds__(512, 2) void k_chunk_out(
    const float* __restrict__ q, const float* __restrict__ k,
    const float* __restrict__ v,
    const float* __restrict__ coef_q, const float* __restrict__ coef_k,
    const float* __restrict__ mask_normer,
    const unsigned short* __restrict__ wsKV, float* __restrict__ out) {
  const int ch = blockIdx.x, h = blockIdx.y, t = threadIdx.x;
  __shared__ alignas(16) short qb[C * PITCH];    // q_bar  [i][a]
  __shared__ alignas(16) short kbf[C * PITCH];   // k_bar  [j][a]
  __shared__ alignas(16) short vT[C * PITCH];    // v^T    [c][j]
  __shared__ alignas(16) short Ab[C * PITCH];    // A      [i][j]
  __shared__ float ssp[C][2];                    // rms partials per row

  const size_t base = (size_t)(h * S + ch * C) * D;
  const float* qp = q + base;
  const float* kp = k + base;
  const float* vp = v + base;
  const float* cq = coef_q + h * S + ch * C;
  const float* ck = coef_k + h * S + ch * C;
  const float* mn = mask_normer + h * S + ch * C;
  const unsigned short* s0p = wsKV + (size_t)(h * NC + ch) * DD;

  // ---- staging rows: thread t -> row i = t>>3, 8 cols c0 = (t&7)*8
  {
    const int i = t >> 3, c0 = (t & 7) * 8;
    const float sq = cq[i] / mn[i];
    const float sk = ck[i];
    bf16x8 wq, wk;
#pragma unroll
    for (int u0 = 0; u0 < 8; u0 += 4) {
      F4 qv = *reinterpret_cast<const F4*>(qp + i * D + c0 + u0);
      F4 kv = *reinterpret_cast<const F4*>(kp + i * D + c0 + u0);
#pragma unroll
      for (int u = 0; u < 4; ++u) {
        wq[u0 + u] = (short)rne_bf16(qv.v[u] * sq);
        wk[u0 + u] = (short)rne_bf16(kv.v[u] * sk);
      }
    }
    *reinterpret_cast<bf16x8*>(&qb[i * PITCH + c0]) = wq;
    *reinterpret_cast<bf16x8*>(&kbf[i * PITCH + c0]) = wk;
  }
  // ---- vT staging: col = t&63, rows i0 = 8*(t>>6)
  {
    const int col = t & 63, i0 = 8 * (t >> 6);
    unsigned pr[4];
#pragma unroll
    for (int u2 = 0; u2 < 4; ++u2) {
      float x0 = vp[(size_t)(i0 + 2 * u2) * D + col];
      float x1 = vp[(size_t)(i0 + 2 * u2 + 1) * D + col];
      pr[u2] = (unsigned)rne_bf16(x0) | ((unsigned)rne_bf16(x1) << 16);
    }
    uint4v wv = {pr[0], pr[1], pr[2], pr[3]};
    *reinterpret_cast<uint4v*>(&vT[col * PITCH + i0]) = wv;
  }
  __syncthreads();

  const int lane = t & 63, w = t >> 6;
  const int arow = lane & 15, kg = lane >> 4;
  const int m = w >> 1, n0 = 2 * (w & 1);
  const int rbase = (16 * m + arow) * PITCH + 8 * kg;

  bf16x8 qa0 = *reinterpret_cast<const bf16x8*>(&qb[rbase]);
  bf16x8 qa1 = *reinterpret_cast<const bf16x8*>(&qb[rbase + 32]);

  // ---- A-stage: wave computes rows 16m..16m+15, cols 16n0..16n0+31
#pragma unroll
  for (int nn = 0; nn < 2; ++nn) {
    const int n = n0 + nn;
    const int bb = (16 * n + arow) * PITCH + 8 * kg;
    bf16x8 b0 = *reinterpret_cast<const bf16x8*>(&kbf[bb]);
    bf16x8 b1 = *reinterpret_cast<const bf16x8*>(&kbf[bb + 32]);
    f32x4 z = {0.f, 0.f, 0.f, 0.f};
    z = __builtin_amdgcn_mfma_f32_16x16x32_bf16(qa0, b0, z, 0, 0, 0);
    z = __builtin_amdgcn_mfma_f32_16x16x32_bf16(qa1, b1, z, 0, 0, 0);
#pragma unroll
    for (int r = 0; r < 4; ++r) {
      int i = 16 * m + 4 * kg + r;
      int j = 16 * n + arow;
      float x = (j <= i) ? z[r] : 0.f;
      Ab[i * PITCH + j] = (short)rne_bf16(x);
    }
  }
  __syncthreads();   // Ab cols for row-tile m written by waves 2m, 2m+1

  // ---- O-stage: wave -> rows 16m.., out col-tiles n0..n0+1
  bf16x8 aa0 = *reinterpret_cast<const bf16x8*>(&Ab[rbase]);
  bf16x8 aa1 = *reinterpret_cast<const bf16x8*>(&Ab[rbase + 32]);
  f32x4 accO[2];
#pragma unroll
  for (int nn = 0; nn < 2; ++nn) {
    const int n = n0 + nn;
    const int bb = (16 * n + arow) * PITCH + 8 * kg;
    const int gb = (16 * n + arow) * D + 8 * kg;
    bf16x8 h0 = *reinterpret_cast<const bf16x8*>(s0p + gb);
    bf16x8 h1 = *reinterpret_cast<const bf16x8*>(s0p + gb + 32);
    bf16x8 v0 = *reinterpret_cast<const bf16x8*>(&vT[bb]);
    bf16x8 v1 = *reinterpret_cast<const bf16x8*>(&vT[bb + 32]);
    f32x4 z = {0.f, 0.f, 0.f, 0.f};
    z = __builtin_amdgcn_mfma_f32_16x16x32_bf16(qa0, h0, z, 0, 0, 0);
    z = __builtin_amdgcn_mfma_f32_16x16x32_bf16(qa1, h1, z, 0, 0, 0);
    z = __builtin_amdgcn_mfma_f32_16x16x32_bf16(aa0, v0, z, 0, 0, 0);
    z = __builtin_amdgcn_mfma_f32_16x16x32_bf16(aa1, v1, z, 0, 0, 0);
    accO[nn] = z;
  }

  // ---- rms partial: reduce over this wave's 32 cols, exchange halves
#pragma unroll
  for (int r = 0; r < 4; ++r) {
    float ss = accO[0][r] * accO[0][r] + accO[1][r] * accO[1][r];
#pragma unroll
    for (int off = 1; off < 16; off <<= 1) ss += __shfl_xor(ss, off);
    if (arow == 0) ssp[16 * m + 4 * kg + r][w & 1] = ss;
  }
  __syncthreads();

  // ---- epilogue: scale + store
  float* op = out + base;
#pragma unroll
  for (int r = 0; r < 4; ++r) {
    const int i = 16 * m + 4 * kg + r;
    const float tot = ssp[i][0] + ssp[i][1];
    const float sc = rsqrtf(tot * (1.0f / D) + 1e-6f);
#pragma unroll
    for (int nn = 0; nn < 2; ++nn)
      op[(size_t)i * D + 16 * (n0 + nn) + arow] = accO[nn][r] * sc;
  }
}

// ---------------------------------------------------------------------------
extern "C" void kernel_launch(void* const* d_in, const int* in_sizes, int n_in,
                              void* d_out, int out_size, void* d_ws, size_t ws_size,
                              hipStream_t stream) {
  (void)in_sizes; (void)n_in; (void)out_size; (void)ws_size;
  const float* q  = (const float*)d_in[0];
  const float* k  = (const float*)d_in[1];
  const float* v  = (const float*)d_in[2];
  const float* cq = (const float*)d_in[3];
  const float* ck = (const float*)d_in[4];
  const float* mn = (const float*)d_in[5];
  float* out = (float*)d_out;

  unsigned short* wsKV = (unsigned short*)d_ws;   // H*NC*D*D bf16 (4 MiB)

  k_chunk_sums<<<dim3(NC, H), dim3(512), 0, stream>>>(k, v, ck, wsKV);
  k_scan<<<dim3(32, H), dim3(64), 0, stream>>>((unsigned*)d_ws);
  k_chunk_out<<<dim3(NC, H), dim3(512), 0, stream>>>(q, k, v, cq, ck, mn, wsKV, out);
}